// Round 7
// baseline (91.010 us; speedup 1.0000x reference)
//
#include <hip/hip_runtime.h>
#include <hip/hip_bf16.h>
#include <math.h>
#include <stdint.h>

#define Bb 16
#define Tt 28
#define Nn 2048
#define Hh 32
#define LAGS 8
#define LN_EPS 1e-5f
#define PSTR 40                      // P row stride (shorts): 80B rows, 16B-aligned
#define LOG2E 1.4426950408889634f

typedef float f4 __attribute__((ext_vector_type(4)));
typedef short s8v __attribute__((ext_vector_type(8)));
typedef unsigned short u16x4 __attribute__((ext_vector_type(4)));
typedef unsigned short u16x8 __attribute__((ext_vector_type(8)));

__device__ __forceinline__ float b2f(unsigned short u) {
    union { unsigned uu; float ff; } x; x.uu = ((unsigned)u) << 16; return x.ff;
}
__device__ __forceinline__ unsigned short f2b(float f) {
    unsigned u = __float_as_uint(f);
    u += 0x7FFFu + ((u >> 16) & 1u);   // RNE
    return (unsigned short)(u >> 16);
}
__device__ __forceinline__ unsigned packbf2(float lo, float hi) {
    __hip_bfloat162 h = __float22bfloat162_rn(make_float2(lo, hi));
    union { __hip_bfloat162 h2; unsigned u; } c; c.h2 = h; return c.u;
}

// ---------------- adj fp32 -> bf16 ----------------
__global__ void k_adjprep(const float* __restrict__ adj, unsigned short* __restrict__ adjb) {
    size_t i = ((size_t)blockIdx.x * 256 + threadIdx.x) * 8;
    f4 a0 = *(const f4*)(adj + i);
    f4 a1 = *(const f4*)(adj + i + 4);
    u16x8 o;
    o[0] = f2b(a0[0]); o[1] = f2b(a0[1]); o[2] = f2b(a0[2]); o[3] = f2b(a0[3]);
    o[4] = f2b(a1[0]); o[5] = f2b(a1[1]); o[6] = f2b(a1[2]); o[7] = f2b(a1[3]);
    *(u16x8*)(adjb + i) = o;
}

// ---------------- delayed signal (f32) ----------------
__global__ void k_delayed(const float* __restrict__ x,
                          const float* __restrict__ dlog,
                          float* __restrict__ dsg) {
    int idx = blockIdx.x * blockDim.x + threadIdx.x; // over B*N
    float w[LAGS];
    float m = -1e30f;
    #pragma unroll
    for (int t = 0; t < LAGS; ++t) m = fmaxf(m, dlog[t]);
    float s = 0.f;
    #pragma unroll
    for (int t = 0; t < LAGS; ++t) { w[t] = __expf(dlog[t] - m); s += w[t]; }
    float inv = 1.f / s;
    if (idx >= Bb * Nn) return;
    int b = idx / Nn, n = idx % Nn;
    float acc = 0.f;
    #pragma unroll
    for (int t = 0; t < LAGS; ++t)
        acc += (w[t] * inv) * x[(size_t)b * Tt * Nn + (size_t)(Tt - 1 - t) * Nn + n];
    dsg[idx] = acc;
}

// ---------------- fused QKV projection -> bf16 Q,K + transposed V ----------------
__global__ void k_qkv(const float* __restrict__ feat,
                      const float* __restrict__ Wq, const float* __restrict__ bq,
                      const float* __restrict__ Wk, const float* __restrict__ bk,
                      const float* __restrict__ Wv, const float* __restrict__ bv,
                      unsigned short* __restrict__ Qbf, unsigned short* __restrict__ Kbf,
                      unsigned short* __restrict__ Vtg) {
    __shared__ float WqT[Hh][Hh + 1], WkT[Hh][Hh + 1], WvT[Hh][Hh + 1];
    __shared__ float f[8][Hh];
    __shared__ __align__(16) unsigned short VT8[Hh][8];
    int tid = threadIdx.x;
    for (int i = tid; i < Hh * Hh; i += 256) {
        int h = i >> 5, k = i & 31;
        WqT[k][h] = Wq[i];
        WkT[k][h] = Wk[i];
        WvT[k][h] = Wv[i];
    }
    int n0 = blockIdx.x * 8;
    f[tid >> 5][tid & 31] = feat[(size_t)n0 * Hh + tid];
    __syncthreads();
    int lr = tid >> 5, h = tid & 31;
    float aq = bq[h], ak = bk[h], av = bv[h];
    #pragma unroll
    for (int k = 0; k < Hh; ++k) {
        float fv = f[lr][k];
        aq += fv * WqT[k][h];
        ak += fv * WkT[k][h];
        av += fv * WvT[k][h];
    }
    size_t o = (size_t)(n0 + lr) * Hh + h;
    Qbf[o] = f2b(aq);
    Kbf[o] = f2b(ak);
    VT8[h][lr] = f2b(av);
    __syncthreads();
    if (tid < 32) {
        int b = n0 >> 11, r0 = n0 & 2047;
        *(u16x8*)(Vtg + ((size_t)b * Hh + tid) * Nn + r0) = *(const u16x8*)&VT8[tid][0];
    }
}

// ---------------- MFMA flash attention: barrier-free, max-free ----------------
// 512 threads = 8 waves = 2 wc (32 n-cols) x 4 wh (32-m quarter of each 128-chunk).
// K/V/adj/ds fragments read directly from global (L2). Only P goes through LDS
// (per-wave private). Linear merge of (pacc, ps, prop) across wh at the end.
__global__ __launch_bounds__(512, 4)
void k_attn(const unsigned short* __restrict__ Qbf,
            const unsigned short* __restrict__ Kbf,
            const unsigned short* __restrict__ Vtg,
            const unsigned short* __restrict__ adjb,
            const float* __restrict__ dsg,
            const float* __restrict__ geo_w,
            const float* __restrict__ feat,
            unsigned short* __restrict__ comb) {
    __shared__ __align__(16) unsigned short Pt[8][32 * PSTR];   // per-wave P [32n][32m]
    __shared__ float mrg[2][2][64][20];                         // merge scratch

    int tid = threadIdx.x;
    int wid = tid >> 6, lane = tid & 63;
    int nl = lane & 15, g4 = lane >> 4;
    int wc = wid & 1, wh = wid >> 1;

    int bid = blockIdx.x;
    int bidl = ((bid & 7) << 6) + (bid >> 3);   // XCD-chunked swizzle (512 = 8*64)
    int b = bidl & 15;
    int nt64 = bidl >> 4;                       // 0..31
    int n0w = nt64 * 64 + wc * 32;

    float geo = 1.f / (1.f + __expf(-geo_w[0]));
    float cs = (1.f - geo) * 0.17677669529663687f * LOG2E;  // fold log2(e) into scale
    float cg = geo * 5.f * LOG2E;

    // Q B-fragments (col = n = nl, k = g4*8+j)
    s8v qf[2];
    #pragma unroll
    for (int nt = 0; nt < 2; ++nt)
        qf[nt] = *(const s8v*)(Qbf + (((size_t)b * Nn + n0w + nt * 16 + nl) << 5) + g4 * 8);

    f4 zf4 = {0.f, 0.f, 0.f, 0.f};
    f4 pacc[2][2];
    #pragma unroll
    for (int nt = 0; nt < 2; ++nt)
        #pragma unroll
        for (int t = 0; t < 2; ++t) pacc[nt][t] = zf4;
    float ps[2] = {0.f, 0.f}, prop[2] = {0.f, 0.f};

    const unsigned short* Kg = Kbf + (size_t)b * Nn * Hh;
    const unsigned short* Vg = Vtg + (size_t)b * Nn * Hh;
    const float* dsb = dsg + (size_t)b * Nn;
    const unsigned short* A0 = adjb + (size_t)(n0w + nl) * Nn;
    const unsigned short* A1 = adjb + (size_t)(n0w + 16 + nl) * Nn;
    unsigned short* Pw = Pt[wid];

    // exp2-based unnormalized softmax term + prop/ps accumulation + P pack
    auto SM = [&](f4 sc, u16x4 av, f4 dv, int nt, int mg, float& ps_, float& pr_) {
        float s0 = cs * sc[0] + cg * b2f(av[0]);
        float s1 = cs * sc[1] + cg * b2f(av[1]);
        float s2 = cs * sc[2] + cg * b2f(av[2]);
        float s3 = cs * sc[3] + cg * b2f(av[3]);
        float p0 = exp2f(s0), p1 = exp2f(s1), p2 = exp2f(s2), p3 = exp2f(s3);
        ps_ += (p0 + p1) + (p2 + p3);
        pr_ += p0 * dv[0] + p1 * dv[1] + p2 * dv[2] + p3 * dv[3];
        uint2 w;
        w.x = packbf2(p0, p1);
        w.y = packbf2(p2, p3);
        *(uint2*)(Pw + (size_t)(nt * 16 + nl) * PSTR + mg * 16 + g4 * 4) = w;
    };

    for (int c = 0; c < Nn / 128; ++c) {
        int mw = c * 128 + wh * 32;   // this wave's 32-m window

        // direct-global fragment loads (L2-resident)
        s8v kf0 = *(const s8v*)(Kg + (size_t)(mw + nl) * Hh + g4 * 8);
        s8v kf1 = *(const s8v*)(Kg + (size_t)(mw + 16 + nl) * Hh + g4 * 8);
        s8v vf0 = *(const s8v*)(Vg + (size_t)nl * Nn + mw + g4 * 8);
        s8v vf1 = *(const s8v*)(Vg + (size_t)(16 + nl) * Nn + mw + g4 * 8);
        f4 dv0 = *(const f4*)(dsb + mw + g4 * 4);
        f4 dv1 = *(const f4*)(dsb + mw + 16 + g4 * 4);
        u16x4 a00 = *(const u16x4*)(A0 + mw + g4 * 4);
        u16x4 a01 = *(const u16x4*)(A0 + mw + 16 + g4 * 4);
        u16x4 a10 = *(const u16x4*)(A1 + mw + g4 * 4);
        u16x4 a11 = *(const u16x4*)(A1 + mw + 16 + g4 * 4);

        // QK^T (swapped): S^T[m][n] = mfma(K_frag, Q_frag)
        f4 sc00 = __builtin_amdgcn_mfma_f32_16x16x32_bf16(kf0, qf[0], zf4, 0, 0, 0);
        f4 sc01 = __builtin_amdgcn_mfma_f32_16x16x32_bf16(kf1, qf[0], zf4, 0, 0, 0);
        f4 sc10 = __builtin_amdgcn_mfma_f32_16x16x32_bf16(kf0, qf[1], zf4, 0, 0, 0);
        f4 sc11 = __builtin_amdgcn_mfma_f32_16x16x32_bf16(kf1, qf[1], zf4, 0, 0, 0);

        SM(sc00, a00, dv0, 0, 0, ps[0], prop[0]);
        SM(sc01, a01, dv1, 0, 1, ps[0], prop[0]);
        SM(sc10, a10, dv0, 1, 0, ps[1], prop[1]);
        SM(sc11, a11, dv1, 1, 1, ps[1], prop[1]);

        // PV: att^T[h][n] += V^T_frag * P^T_frag over this 32-m window
        s8v pb0 = *(const s8v*)(Pw + (size_t)(0 * 16 + nl) * PSTR + g4 * 8);
        s8v pb1 = *(const s8v*)(Pw + (size_t)(1 * 16 + nl) * PSTR + g4 * 8);
        pacc[0][0] = __builtin_amdgcn_mfma_f32_16x16x32_bf16(vf0, pb0, pacc[0][0], 0, 0, 0);
        pacc[0][1] = __builtin_amdgcn_mfma_f32_16x16x32_bf16(vf1, pb0, pacc[0][1], 0, 0, 0);
        pacc[1][0] = __builtin_amdgcn_mfma_f32_16x16x32_bf16(vf0, pb1, pacc[1][0], 0, 0, 0);
        pacc[1][1] = __builtin_amdgcn_mfma_f32_16x16x32_bf16(vf1, pb1, pacc[1][1], 0, 0, 0);
    }

    // cross-lane reduce of the linear scalars (per n-col: sum over g4 groups)
    #pragma unroll
    for (int nt = 0; nt < 2; ++nt) {
        ps[nt] += __shfl_xor(ps[nt], 16);
        ps[nt] += __shfl_xor(ps[nt], 32);
        prop[nt] += __shfl_xor(prop[nt], 16);
        prop[nt] += __shfl_xor(prop[nt], 32);
    }

    // ---- linear merge across the 4 wh waves (tree: 4 -> 2 -> 1) ----
    __syncthreads();
    if (wh & 1) {
        float* d = &mrg[wh >> 1][wc][lane][0];
        #pragma unroll
        for (int nt = 0; nt < 2; ++nt)
            #pragma unroll
            for (int t = 0; t < 2; ++t)
                #pragma unroll
                for (int r = 0; r < 4; ++r) d[nt * 8 + t * 4 + r] = pacc[nt][t][r];
        d[16] = ps[0]; d[17] = ps[1]; d[18] = prop[0]; d[19] = prop[1];
    }
    __syncthreads();
    if (!(wh & 1)) {
        const float* d = &mrg[wh >> 1][wc][lane][0];
        #pragma unroll
        for (int nt = 0; nt < 2; ++nt)
            #pragma unroll
            for (int t = 0; t < 2; ++t)
                #pragma unroll
                for (int r = 0; r < 4; ++r) pacc[nt][t][r] += d[nt * 8 + t * 4 + r];
        ps[0] += d[16]; ps[1] += d[17]; prop[0] += d[18]; prop[1] += d[19];
    }
    __syncthreads();
    if (wh == 2) {
        float* d = &mrg[0][wc][lane][0];
        #pragma unroll
        for (int nt = 0; nt < 2; ++nt)
            #pragma unroll
            for (int t = 0; t < 2; ++t)
                #pragma unroll
                for (int r = 0; r < 4; ++r) d[nt * 8 + t * 4 + r] = pacc[nt][t][r];
        d[16] = ps[0]; d[17] = ps[1]; d[18] = prop[0]; d[19] = prop[1];
    }
    __syncthreads();
    if (wh == 0) {
        const float* d = &mrg[0][wc][lane][0];
        #pragma unroll
        for (int nt = 0; nt < 2; ++nt)
            #pragma unroll
            for (int t = 0; t < 2; ++t)
                #pragma unroll
                for (int r = 0; r < 4; ++r) pacc[nt][t][r] += d[nt * 8 + t * 4 + r];
        ps[0] += d[16]; ps[1] += d[17]; prop[0] += d[18]; prop[1] += d[19];

        // epilogue: comb(bf16) = feat + attended + 0.1*prop
        #pragma unroll
        for (int nt = 0; nt < 2; ++nt) {
            float invS = 1.f / ps[nt];
            float pp = prop[nt] * invS * 0.1f;
            size_t o = ((size_t)b * Nn + n0w + nt * 16 + nl) * Hh;
            #pragma unroll
            for (int t = 0; t < 2; ++t) {
                f4 fv = *(const f4*)(feat + o + t * 16 + g4 * 4);
                f4 ov = fv + pacc[nt][t] * invS;
                u16x4 cw;
                cw[0] = f2b(ov[0] + pp);
                cw[1] = f2b(ov[1] + pp);
                cw[2] = f2b(ov[2] + pp);
                cw[3] = f2b(ov[3] + pp);
                *(u16x4*)(comb + o + t * 16 + g4 * 4) = cw;
            }
        }
    }
}

// ---------------- output projection + LayerNorm (bf16 comb in) ----------------
__global__ void k_projln(const unsigned short* __restrict__ comb,
                         const float* __restrict__ Wo, const float* __restrict__ bo,
                         const float* __restrict__ gamma, const float* __restrict__ beta,
                         float* __restrict__ out) {
    __shared__ float WoT[Hh][Hh + 1];
    __shared__ float f[8][Hh];
    int tid = threadIdx.x;
    for (int i = tid; i < Hh * Hh; i += 256) {
        WoT[i & 31][i >> 5] = Wo[i];
    }
    int row0 = blockIdx.x * 8;
    f[tid >> 5][tid & 31] = b2f(comb[(size_t)row0 * Hh + tid]);
    __syncthreads();
    int lr = tid >> 5, h = tid & 31;
    float a = bo[h];
    #pragma unroll
    for (int k = 0; k < Hh; ++k) a += f[lr][k] * WoT[k][h];
    float mu = a;
    #pragma unroll
    for (int w = 1; w < 32; w <<= 1) mu += __shfl_xor(mu, w);
    mu *= (1.f / 32.f);
    float d = a - mu;
    float v = d * d;
    #pragma unroll
    for (int w = 1; w < 32; w <<= 1) v += __shfl_xor(v, w);
    v *= (1.f / 32.f);
    out[(size_t)row0 * Hh + tid] = d * rsqrtf(v + LN_EPS) * gamma[h] + beta[h];
}

extern "C" void kernel_launch(void* const* d_in, const int* in_sizes, int n_in,
                              void* d_out, int out_size, void* d_ws, size_t ws_size,
                              hipStream_t stream) {
    const float* x     = (const float*)d_in[0];
    const float* feat  = (const float*)d_in[1];
    const float* dlog  = (const float*)d_in[2];
    const float* Wq    = (const float*)d_in[3];
    const float* bq    = (const float*)d_in[4];
    const float* Wk    = (const float*)d_in[5];
    const float* bk    = (const float*)d_in[6];
    const float* Wv    = (const float*)d_in[7];
    const float* bv    = (const float*)d_in[8];
    const float* adj   = (const float*)d_in[9];
    const float* geo   = (const float*)d_in[10];
    const float* Wo    = (const float*)d_in[11];
    const float* bo    = (const float*)d_in[12];
    const float* gamma = (const float*)d_in[13];
    const float* beta  = (const float*)d_in[14];
    float* out = (float*)d_out;

    char* w = (char*)d_ws;
    unsigned short* Qbf  = (unsigned short*)w;  w += (size_t)Bb * Nn * Hh * 2;
    unsigned short* Kbf  = (unsigned short*)w;  w += (size_t)Bb * Nn * Hh * 2;
    unsigned short* Vtg  = (unsigned short*)w;  w += (size_t)Bb * Nn * Hh * 2;
    unsigned short* adjb = (unsigned short*)w;  w += (size_t)Nn * Nn * 2;
    float* dsg           = (float*)w;           w += (size_t)Bb * Nn * 4;
    unsigned short* comb = (unsigned short*)w;

    k_adjprep<<<(Nn * Nn) / (256 * 8), 256, 0, stream>>>(adj, adjb);
    k_delayed<<<(Bb * Nn + 255) / 256, 256, 0, stream>>>(x, dlog, dsg);
    k_qkv<<<Bb * Nn / 8, 256, 0, stream>>>(feat, Wq, bq, Wk, bk, Wv, bv, Qbf, Kbf, Vtg);
    k_attn<<<512, 512, 0, stream>>>(Qbf, Kbf, Vtg, adjb, dsg, geo, feat, comb);
    k_projln<<<Bb * Nn / 8, 256, 0, stream>>>(comb, Wo, bo, gamma, beta, out);
}